// Round 1
// baseline (640.582 us; speedup 1.0000x reference)
//
#include <hip/hip_runtime.h>

#define BS 4
#define SEQ 2048
#define DIM 1024
#define NH 16
#define HD 64
#define T_TOK (BS * SEQ)   // 8192

using f32x4 = __attribute__((ext_vector_type(4))) float;
using s16x8 = __attribute__((ext_vector_type(8))) short;
using u32x4 = __attribute__((ext_vector_type(4))) unsigned int;

static __device__ __forceinline__ unsigned short f2bf(float f) {
    unsigned int u = __float_as_uint(f);
    u += 0x7FFF + ((u >> 16) & 1);   // RNE
    return (unsigned short)(u >> 16);
}

// Stage a ROWSx64 bf16 tile into LDS with st-style XOR swizzle:
// logical element (row, col) lives at LDS byte (row*128 + col*2) ^ ((row&7)<<4).
// Each thread writes one 16B granule per pass; XOR only touches bits 4..6 so
// granule alignment is preserved. Source is row-major [*, ldsrc] f32 or bf16.
template<int ROWS, bool F32SRC>
static __device__ __forceinline__ void stage_tile(unsigned short* lds, const void* src,
                                                  long row0, long col0, long ldsrc, int tid) {
#pragma unroll
    for (int p = 0; p < ROWS / 32; ++p) {
        int d = (p * 256 + tid) * 16;       // logical byte offset in tile
        int row = d >> 7;                   // 128 B per row
        int col = (d & 127) >> 1;           // element col (multiple of 8)
        int dst = d ^ ((row & 7) << 4);
        if constexpr (F32SRC) {
            const float* s = (const float*)src + (row0 + row) * ldsrc + col0 + col;
            f32x4 v0 = *(const f32x4*)s;
            f32x4 v1 = *(const f32x4*)(s + 4);
            s16x8 o;
            o[0] = (short)f2bf(v0[0]); o[1] = (short)f2bf(v0[1]);
            o[2] = (short)f2bf(v0[2]); o[3] = (short)f2bf(v0[3]);
            o[4] = (short)f2bf(v1[0]); o[5] = (short)f2bf(v1[1]);
            o[6] = (short)f2bf(v1[2]); o[7] = (short)f2bf(v1[3]);
            *(s16x8*)((char*)lds + dst) = o;
        } else {
            const unsigned short* s = (const unsigned short*)src + (row0 + row) * ldsrc + col0 + col;
            *(u32x4*)((char*)lds + dst) = *(const u32x4*)(const void*)s;
        }
    }
}

static __device__ __forceinline__ s16x8 lds_frag(const unsigned short* lds, int row, int kel) {
    int byte = (row * 128 + kel * 2) ^ ((row & 7) << 4);
    return *(const s16x8*)((const char*)lds + byte);
}

// C = A * B^T (+bias)*alpha.  A: [M][K] (f32 or bf16), B: [N][K] (f32 or bf16).
// Normal: C[M][N] (ldc=N).  TRANS_OUT: C[N][M] (ldc=M), via swapped mfma operands.
template<bool A_F32, bool B_F32, bool TRANS_OUT, bool OUT_BF16>
__global__ __launch_bounds__(256, 2)
void gemm_bt(const void* __restrict__ Ap, const void* __restrict__ Bp,
             const float* __restrict__ bias, float alpha,
             void* __restrict__ Cp, int K, long ldc) {
    __shared__ unsigned short As[128 * 64];
    __shared__ unsigned short Bs[128 * 64];

    const int tid = threadIdx.x;
    const int lane = tid & 63;
    const int wid = tid >> 6;
    const long bm = (long)blockIdx.x * 128;
    const long bn = (long)blockIdx.y * 128;
    const int wm = (wid >> 1) * 64;
    const int wn = (wid & 1) * 64;

    f32x4 acc[4][4] = {};

#pragma unroll 1
    for (int k0 = 0; k0 < K; k0 += 64) {
        stage_tile<128, A_F32>(As, Ap, bm, k0, K, tid);
        stage_tile<128, B_F32>(Bs, Bp, bn, k0, K, tid);
        __syncthreads();
#pragma unroll
        for (int kk = 0; kk < 2; ++kk) {
            const int kel = kk * 32 + (lane >> 4) * 8;
            s16x8 af[4], bf[4];
#pragma unroll
            for (int i = 0; i < 4; ++i) {
                af[i] = lds_frag(As, wm + i * 16 + (lane & 15), kel);
                bf[i] = lds_frag(Bs, wn + i * 16 + (lane & 15), kel);
            }
#pragma unroll
            for (int i = 0; i < 4; ++i)
#pragma unroll
                for (int j = 0; j < 4; ++j) {
                    if constexpr (TRANS_OUT)
                        acc[i][j] = __builtin_amdgcn_mfma_f32_16x16x32_bf16(bf[j], af[i], acc[i][j], 0, 0, 0);
                    else
                        acc[i][j] = __builtin_amdgcn_mfma_f32_16x16x32_bf16(af[i], bf[j], acc[i][j], 0, 0, 0);
                }
        }
        __syncthreads();
    }

#pragma unroll
    for (int i = 0; i < 4; ++i)
#pragma unroll
        for (int j = 0; j < 4; ++j)
#pragma unroll
            for (int r = 0; r < 4; ++r) {
                if constexpr (!TRANS_OUT) {
                    long row = bm + wm + i * 16 + ((lane >> 4) * 4 + r);
                    long col = bn + wn + j * 16 + (lane & 15);
                    float v = (acc[i][j][r] + bias[col]) * alpha;
                    if constexpr (OUT_BF16)
                        ((unsigned short*)Cp)[row * ldc + col] = f2bf(v);
                    else
                        ((float*)Cp)[row * ldc + col] = v;
                } else {
                    long o = bn + wn + j * 16 + ((lane >> 4) * 4 + r);
                    long t = bm + wm + i * 16 + (lane & 15);
                    float v = (acc[i][j][r] + bias[o]) * alpha;
                    ((unsigned short*)Cp)[o * ldc + t] = f2bf(v);
                }
            }
}

// Flash attention: one block per (128 q-rows, head, batch). 4 waves x 32 q-rows.
// Qb/Kb: bf16 [T_TOK][DIM]; Vt: bf16 [DIM][T_TOK]; Ctx out: bf16 [T_TOK][DIM].
__global__ __launch_bounds__(256, 2)
void flash_attn(const unsigned short* __restrict__ Qb,
                const unsigned short* __restrict__ Kb,
                const unsigned short* __restrict__ Vt,
                const int* __restrict__ mask,
                unsigned short* __restrict__ Ctx) {
    __shared__ unsigned short Qs[128 * 64];
    __shared__ unsigned short Ks[64 * 64];
    __shared__ unsigned short Vts[64 * 64];
    __shared__ unsigned short Ps[128 * 64];
    __shared__ float maskadd[64];

    const int tid = threadIdx.x;
    const int lane = tid & 63;
    const int w = tid >> 6;
    const long qt = (long)blockIdx.x * 128;
    const int h = blockIdx.y;
    const int b = blockIdx.z;
    const long base_t = (long)b * SEQ;

    // Q tile staged once (guarded by the first in-loop barrier)
    stage_tile<128, false>(Qs, Qb, base_t + qt, h * 64, DIM, tid);

    float m_st[2][4], l_st[2][4];
    f32x4 o_acc[2][4] = {};
#pragma unroll
    for (int i = 0; i < 2; ++i)
#pragma unroll
        for (int r = 0; r < 4; ++r) { m_st[i][r] = -1e30f; l_st[i][r] = 0.f; }

#pragma unroll 1
    for (int kv = 0; kv < SEQ; kv += 64) {
        stage_tile<64, false>(Ks, Kb, base_t + kv, h * 64, DIM, tid);
        stage_tile<64, false>(Vts, Vt, h * 64, base_t + kv, T_TOK, tid);
        if (tid < 64) maskadd[tid] = mask[b * SEQ + kv + tid] ? 0.f : -1e30f;
        __syncthreads();

        // S = Q K^T  (rows: this wave's 32 q, cols: 64 keys)
        f32x4 s[2][4] = {};
#pragma unroll
        for (int kk = 0; kk < 2; ++kk) {
            const int kel = kk * 32 + (lane >> 4) * 8;
            s16x8 qf[2], kf[4];
#pragma unroll
            for (int i = 0; i < 2; ++i) qf[i] = lds_frag(Qs, w * 32 + i * 16 + (lane & 15), kel);
#pragma unroll
            for (int j = 0; j < 4; ++j) kf[j] = lds_frag(Ks, j * 16 + (lane & 15), kel);
#pragma unroll
            for (int i = 0; i < 2; ++i)
#pragma unroll
                for (int j = 0; j < 4; ++j)
                    s[i][j] = __builtin_amdgcn_mfma_f32_16x16x32_bf16(qf[i], kf[j], s[i][j], 0, 0, 0);
        }

        // online softmax per q-row; each row lives in 16 lanes (same lane>>4)
#pragma unroll
        for (int i = 0; i < 2; ++i)
#pragma unroll
            for (int r = 0; r < 4; ++r) {
                float mx = -1e30f;
#pragma unroll
                for (int j = 0; j < 4; ++j) {
                    s[i][j][r] += maskadd[j * 16 + (lane & 15)];
                    mx = fmaxf(mx, s[i][j][r]);
                }
                mx = fmaxf(mx, __shfl_xor(mx, 1));
                mx = fmaxf(mx, __shfl_xor(mx, 2));
                mx = fmaxf(mx, __shfl_xor(mx, 4));
                mx = fmaxf(mx, __shfl_xor(mx, 8));
                const float m_new = fmaxf(m_st[i][r], mx);
                const float corr = __expf(m_st[i][r] - m_new);
                float rs = 0.f;
#pragma unroll
                for (int j = 0; j < 4; ++j) {
                    float p = __expf(s[i][j][r] - m_new);
                    s[i][j][r] = p;
                    rs += p;
                }
                rs += __shfl_xor(rs, 1);
                rs += __shfl_xor(rs, 2);
                rs += __shfl_xor(rs, 4);
                rs += __shfl_xor(rs, 8);
                l_st[i][r] = l_st[i][r] * corr + rs;
                m_st[i][r] = m_new;
#pragma unroll
                for (int j = 0; j < 4; ++j) o_acc[i][j][r] *= corr;
                // P -> LDS (bf16, same swizzle as frag reader)
                const int prow = w * 32 + i * 16 + (lane >> 4) * 4 + r;
#pragma unroll
                for (int j = 0; j < 4; ++j) {
                    const int pcol = j * 16 + (lane & 15);
                    const int byte = (prow * 128 + pcol * 2) ^ ((prow & 7) << 4);
                    *(unsigned short*)((char*)Ps + byte) = f2bf(s[i][j][r]);
                }
            }

        // O += P * V   (A = P rows, B = Vt rows = head-dim cols)
#pragma unroll
        for (int kk = 0; kk < 2; ++kk) {
            const int kel = kk * 32 + (lane >> 4) * 8;
            s16x8 pf[2], vf[4];
#pragma unroll
            for (int i = 0; i < 2; ++i) pf[i] = lds_frag(Ps, w * 32 + i * 16 + (lane & 15), kel);
#pragma unroll
            for (int j = 0; j < 4; ++j) vf[j] = lds_frag(Vts, j * 16 + (lane & 15), kel);
#pragma unroll
            for (int i = 0; i < 2; ++i)
#pragma unroll
                for (int j = 0; j < 4; ++j)
                    o_acc[i][j] = __builtin_amdgcn_mfma_f32_16x16x32_bf16(pf[i], vf[j], o_acc[i][j], 0, 0, 0);
        }
        __syncthreads();
    }

    // epilogue: normalize and store context bf16 [tok][DIM]
#pragma unroll
    for (int i = 0; i < 2; ++i)
#pragma unroll
        for (int j = 0; j < 4; ++j)
#pragma unroll
            for (int r = 0; r < 4; ++r) {
                const float v = o_acc[i][j][r] / l_st[i][r];
                const long t = base_t + qt + w * 32 + i * 16 + (lane >> 4) * 4 + r;
                const int col = h * 64 + j * 16 + (lane & 15);
                Ctx[t * DIM + col] = f2bf(v);
            }
}

extern "C" void kernel_launch(void* const* d_in, const int* in_sizes, int n_in,
                              void* d_out, int out_size, void* d_ws, size_t ws_size,
                              hipStream_t stream) {
    const float* q  = (const float*)d_in[0];
    const float* k  = (const float*)d_in[1];
    const float* v  = (const float*)d_in[2];
    const int* mask = (const int*)d_in[3];
    const float* Wq = (const float*)d_in[4];
    const float* bq = (const float*)d_in[5];
    const float* Wk = (const float*)d_in[6];
    const float* bk = (const float*)d_in[7];
    const float* Wv = (const float*)d_in[8];
    const float* bv = (const float*)d_in[9];
    const float* Wo = (const float*)d_in[10];
    const float* bo = (const float*)d_in[11];
    float* out = (float*)d_out;

    unsigned short* Qb  = (unsigned short*)d_ws;
    unsigned short* Kb  = Qb + (size_t)T_TOK * DIM;
    unsigned short* Vt  = Kb + (size_t)T_TOK * DIM;
    unsigned short* Ctx = Vt + (size_t)T_TOK * DIM;

    const dim3 g(T_TOK / 128, DIM / 128);
    const float inv_sqrt_hd = 0.125f;

    gemm_bt<true, true, false, true><<<g, 256, 0, stream>>>(q, Wq, bq, inv_sqrt_hd, Qb, DIM, DIM);
    gemm_bt<true, true, false, true><<<g, 256, 0, stream>>>(k, Wk, bk, 1.0f, Kb, DIM, DIM);
    gemm_bt<true, true, true,  true><<<g, 256, 0, stream>>>(v, Wv, bv, 1.0f, Vt, DIM, T_TOK);
    flash_attn<<<dim3(SEQ / 128, NH, BS), 256, 0, stream>>>(Qb, Kb, Vt, mask, Ctx);
    gemm_bt<false, true, false, false><<<g, 256, 0, stream>>>(Ctx, Wo, bo, 1.0f, out, DIM, DIM);
}